// Round 1
// baseline (232.213 us; speedup 1.0000x reference)
//
#include <hip/hip_runtime.h>
#include <stdint.h>

typedef __attribute__((ext_vector_type(4))) int i32x4;

#define N_FRAMES 16386
#define D_DIM    1024
#define O_DIM    2048
#define L_CTX    3
#define K_DIM    3072   // D_DIM * L_CTX
#define T_DIM    16384  // N_FRAMES - L_CTX + 1

// workspace byte offsets
#define WS_MM     0u        // 2 x uint (flipped min/max)
#define WS_PARAMS 64u       // Params
#define WS_CO     256u      // O_DIM int32
#define WS_S      16384u    // N_FRAMES int32
#define WS_CT     98304u    // T_DIM int32
#define WS_QW     262144u   // O_DIM*K_DIM int8
#define WS_QX     8388608u  // N_FRAMES*D_DIM int8  (ends ~25.2 MB)

struct Params {
  float w_scale, in_scale, cscale;
  int   w_zp, in_zp, konst;
};

typedef __attribute__((address_space(3))) void       lds_void;
typedef const __attribute__((address_space(1))) void gbl_void;

__device__ __forceinline__ unsigned flip_f(float f) {
  unsigned u = __float_as_uint(f);
  return (u & 0x80000000u) ? ~u : (u | 0x80000000u);
}
__device__ __forceinline__ float unflip_f(unsigned v) {
  unsigned u = (v & 0x80000000u) ? (v ^ 0x80000000u) : ~v;
  return __uint_as_float(u);
}

__global__ void init_kernel(unsigned* mm) {
  mm[0] = 0xFFFFFFFFu;  // min accumulator (flipped space)
  mm[1] = 0u;           // max accumulator
}

__global__ __launch_bounds__(256) void wminmax_kernel(const float4* __restrict__ w,
                                                      unsigned* mm, int n4) {
  unsigned lmin = 0xFFFFFFFFu, lmax = 0u;
  for (int i = blockIdx.x * blockDim.x + threadIdx.x; i < n4; i += gridDim.x * blockDim.x) {
    float4 v = w[i];
    unsigned a = flip_f(v.x), b = flip_f(v.y), c = flip_f(v.z), d = flip_f(v.w);
    lmin = min(lmin, min(min(a, b), min(c, d)));
    lmax = max(lmax, max(max(a, b), max(c, d)));
  }
#pragma unroll
  for (int off = 32; off > 0; off >>= 1) {
    lmin = min(lmin, (unsigned)__shfl_xor((int)lmin, off, 64));
    lmax = max(lmax, (unsigned)__shfl_xor((int)lmax, off, 64));
  }
  if ((threadIdx.x & 63) == 0) {
    atomicMin(&mm[0], lmin);
    atomicMax(&mm[1], lmax);
  }
}

__global__ void params_kernel(const unsigned* __restrict__ mm,
                              const float* __restrict__ in_min,
                              const float* __restrict__ in_max,
                              Params* __restrict__ p) {
  float wmin = unflip_f(mm[0]);
  float wmax = unflip_f(mm[1]);
  float ws = (wmax - wmin) / 254.0f;
  float wz = -127.0f - wmin / ws;
  wz = fminf(fmaxf(wz, -127.0f), 127.0f);
  int wzp = (int)wz;  // trunc toward zero, matches jnp.trunc->int
  float imin = *in_min, imax = *in_max;
  float is = (imax - imin) / 254.0f;
  float iz = -127.0f - imin / is;
  iz = fminf(fmaxf(iz, -127.0f), 127.0f);
  int izp = (int)iz;
  p->w_scale = ws; p->in_scale = is; p->cscale = is * ws;
  p->w_zp = wzp;   p->in_zp = izp;
  p->konst = K_DIM * wzp * izp;
}

// one block per output row o: quantize weight row, write dequant, rowsum -> co
__global__ __launch_bounds__(256) void quantw_kernel(
    const float* __restrict__ w, const float* __restrict__ bias,
    const Params* __restrict__ p, int8_t* __restrict__ qw,
    int* __restrict__ co, float* __restrict__ dq, float* __restrict__ bias_out) {
  const int o = blockIdx.x;
  const float ws = p->w_scale;
  const float zpf = (float)p->w_zp;
  const float* wrow = w + (size_t)o * K_DIM;
  float* dqrow = dq + (size_t)o * K_DIM;
  int8_t* qrow = qw + (size_t)o * K_DIM;
  int sum = 0;
#pragma unroll
  for (int pass = 0; pass < 3; ++pass) {
    const int k = (pass << 10) + (threadIdx.x << 2);
    float4 v = *(const float4*)(wrow + k);
    int8_t c0 = (int8_t)(int)rintf(v.x / ws + zpf);
    int8_t c1 = (int8_t)(int)rintf(v.y / ws + zpf);
    int8_t c2 = (int8_t)(int)rintf(v.z / ws + zpf);
    int8_t c3 = (int8_t)(int)rintf(v.w / ws + zpf);
    sum += (int)c0 + (int)c1 + (int)c2 + (int)c3;
    unsigned packed = (unsigned)(uint8_t)c0 | ((unsigned)(uint8_t)c1 << 8)
                    | ((unsigned)(uint8_t)c2 << 16) | ((unsigned)(uint8_t)c3 << 24);
    *(unsigned*)(qrow + k) = packed;
    float4 d;
    d.x = ((float)c0 - zpf) * ws;
    d.y = ((float)c1 - zpf) * ws;
    d.z = ((float)c2 - zpf) * ws;
    d.w = ((float)c3 - zpf) * ws;
    *(float4*)(dqrow + k) = d;
  }
  __shared__ int red[4];
#pragma unroll
  for (int off = 32; off > 0; off >>= 1) sum += __shfl_xor(sum, off, 64);
  if ((threadIdx.x & 63) == 0) red[threadIdx.x >> 6] = sum;
  __syncthreads();
  if (threadIdx.x == 0) {
    int tot = red[0] + red[1] + red[2] + red[3];
    co[o] = -p->in_zp * tot;
    bias_out[o] = bias[o];
  }
}

// one block per frame n: quantize input frame, frame sum -> s[n]
__global__ __launch_bounds__(256) void quantx_kernel(
    const float* __restrict__ x, const Params* __restrict__ p,
    int8_t* __restrict__ qx, int* __restrict__ s) {
  const int n = blockIdx.x;
  const float is = p->in_scale;
  const float zpf = (float)p->in_zp;
  const float4 v = *((const float4*)(x + (size_t)n * D_DIM) + threadIdx.x);
  int8_t c0 = (int8_t)(int)rintf(v.x / is + zpf);
  int8_t c1 = (int8_t)(int)rintf(v.y / is + zpf);
  int8_t c2 = (int8_t)(int)rintf(v.z / is + zpf);
  int8_t c3 = (int8_t)(int)rintf(v.w / is + zpf);
  unsigned packed = (unsigned)(uint8_t)c0 | ((unsigned)(uint8_t)c1 << 8)
                  | ((unsigned)(uint8_t)c2 << 16) | ((unsigned)(uint8_t)c3 << 24);
  ((unsigned*)(qx + (size_t)n * D_DIM))[threadIdx.x] = packed;
  int sum = (int)c0 + (int)c1 + (int)c2 + (int)c3;
  __shared__ int red[4];
#pragma unroll
  for (int off = 32; off > 0; off >>= 1) sum += __shfl_xor(sum, off, 64);
  if ((threadIdx.x & 63) == 0) red[threadIdx.x >> 6] = sum;
  __syncthreads();
  if (threadIdx.x == 0) s[n] = red[0] + red[1] + red[2] + red[3];
}

// ct[t] = konst - w_zp * (s[t] + s[t+1] + s[t+2])
__global__ __launch_bounds__(256) void ct_kernel(const int* __restrict__ s,
                                                 const Params* __restrict__ p,
                                                 int* __restrict__ ct) {
  const int t = blockIdx.x * blockDim.x + threadIdx.x;
  if (t < T_DIM) ct[t] = p->konst - p->w_zp * (s[t] + s[t + 1] + s[t + 2]);
}

// int8 NT GEMM: C[t,o] = sum_k qx[t*D + k] * qw[o*K + k]; epilogue dequant+bias
__global__ __launch_bounds__(256) void gemm_kernel(
    const int8_t* __restrict__ qx, const int8_t* __restrict__ qw,
    const int* __restrict__ co, const int* __restrict__ ct,
    const float* __restrict__ bias, const Params* __restrict__ p,
    float* __restrict__ out) {
  __shared__ int8_t As[128][64];
  __shared__ int8_t Bs[128][64];

  const int bid = blockIdx.x;
  const int tn = bid & 15;   // 16 N tiles
  const int tm = bid >> 4;   // 128 M tiles
  const int lane = threadIdx.x & 63;
  const int wave = threadIdx.x >> 6;
  const int wm = wave >> 1, wn = wave & 1;
  const int lr = lane & 15;
  const int kg = lane >> 4;

  const int m0 = tm << 7, n0 = tn << 7;

  i32x4 acc[4][4] = {};

  // staging geometry: lane l writes LDS bytes [wavebase + l*16, +16)
  const int srow = (wave << 4) + (lane >> 2);  // 0..63 within a 64-row round
  const int scol = (lane & 3) << 4;            // 0,16,32,48

  for (int kt = 0; kt < K_DIM / 64; ++kt) {
#pragma unroll
    for (int r = 0; r < 2; ++r) {
      const int8_t* srcA = qx + (size_t)(m0 + (r << 6) + srow) * D_DIM + (kt << 6) + scol;
      __builtin_amdgcn_global_load_lds((gbl_void*)srcA,
          (lds_void*)&As[(r << 6) + (wave << 4)][0], 16, 0, 0);
      const int8_t* srcB = qw + (size_t)(n0 + (r << 6) + srow) * K_DIM + (kt << 6) + scol;
      __builtin_amdgcn_global_load_lds((gbl_void*)srcB,
          (lds_void*)&Bs[(r << 6) + (wave << 4)][0], 16, 0, 0);
    }
    __syncthreads();  // compiler drains vmcnt before s_barrier

    i32x4 af[4], bf[4];
#pragma unroll
    for (int m = 0; m < 4; ++m)
      af[m] = *(const i32x4*)&As[(wm << 6) + (m << 4) + lr][kg << 4];
#pragma unroll
    for (int n = 0; n < 4; ++n)
      bf[n] = *(const i32x4*)&Bs[(wn << 6) + (n << 4) + lr][kg << 4];
#pragma unroll
    for (int m = 0; m < 4; ++m)
#pragma unroll
      for (int n = 0; n < 4; ++n)
        acc[m][n] = __builtin_amdgcn_mfma_i32_16x16x64_i8(af[m], bf[n], acc[m][n], 0, 0, 0);
    __syncthreads();
  }

  const float cscale = p->cscale;
#pragma unroll
  for (int m = 0; m < 4; ++m) {
    const int tbase = m0 + (wm << 6) + (m << 4) + (kg << 2);
#pragma unroll
    for (int n = 0; n < 4; ++n) {
      const int o_ = n0 + (wn << 6) + (n << 4) + lr;
      const int cov = co[o_];
      const float bo = bias[o_];
#pragma unroll
      for (int r = 0; r < 4; ++r) {
        const int t_ = tbase + r;
        out[(size_t)t_ * O_DIM + o_] = (float)(acc[m][n][r] + cov + ct[t_]) * cscale + bo;
      }
    }
  }
}

extern "C" void kernel_launch(void* const* d_in, const int* in_sizes, int n_in,
                              void* d_out, int out_size, void* d_ws, size_t ws_size,
                              hipStream_t stream) {
  const float* x      = (const float*)d_in[0];
  const float* w      = (const float*)d_in[1];
  const float* bias   = (const float*)d_in[2];
  const float* in_min = (const float*)d_in[3];
  const float* in_max = (const float*)d_in[4];
  float* out = (float*)d_out;

  uint8_t* ws = (uint8_t*)d_ws;
  unsigned* mm = (unsigned*)(ws + WS_MM);
  Params*   prm = (Params*)(ws + WS_PARAMS);
  int*      co = (int*)(ws + WS_CO);
  int*      s  = (int*)(ws + WS_S);
  int*      ct = (int*)(ws + WS_CT);
  int8_t*   qw = (int8_t*)(ws + WS_QW);
  int8_t*   qx = (int8_t*)(ws + WS_QX);

  float* dq_out   = out + (size_t)T_DIM * O_DIM;            // output 1: dequant W
  float* bias_out = dq_out + (size_t)O_DIM * K_DIM;         // output 2: bias copy

  init_kernel<<<1, 1, 0, stream>>>(mm);
  wminmax_kernel<<<512, 256, 0, stream>>>((const float4*)w, mm, O_DIM * K_DIM / 4);
  params_kernel<<<1, 1, 0, stream>>>(mm, in_min, in_max, prm);
  quantw_kernel<<<O_DIM, 256, 0, stream>>>(w, bias, prm, qw, co, dq_out, bias_out);
  quantx_kernel<<<N_FRAMES, 256, 0, stream>>>(x, prm, qx, s);
  ct_kernel<<<T_DIM / 256, 256, 0, stream>>>(s, prm, ct);
  gemm_kernel<<<(T_DIM / 128) * (O_DIM / 128), 256, 0, stream>>>(qx, qw, co, ct, bias, prm, out);
}